// Round 11
// baseline (162.174 us; speedup 1.0000x reference)
//
#include <hip/hip_runtime.h>
#include <cstdint>

#define IN_F   4096
#define OUT_F  14336
#define GROUP  128
#define KROT   8
#define BATCH  16
#define NJP    1792           // packed words per weight row
#define NG     32             // quant groups

typedef __attribute__((ext_vector_type(8))) short short8;  // 8 bf16
typedef __attribute__((ext_vector_type(4))) float f32x4;

// Module-scope scratch (no d_ws dependence).
__device__ uint32_t g_xa[BATCH * IN_F / 2];    // rotated activations, bf16 pairs
__device__ float    g_rs[NG * BATCH];          // per-(group,row) sums of bf16 acts
__device__ float    g_part[4 * BATCH * OUT_F]; // 4 K-chunk fp32 partials
__device__ int      g_sem[112];                // per-n-slice arrival counters

static __device__ __forceinline__ unsigned short f2bf(float f) {
    union { float f; uint32_t i; } v; v.f = f;
    uint32_t u = v.i;
    uint32_t r = u + 0x7FFFu + ((u >> 16) & 1u);  // RNE
    return (unsigned short)(r >> 16);
}
static __device__ __forceinline__ float bf2f(uint32_t u16) {
    union { uint32_t i; float f; } v; v.i = u16 << 16; return v.f;
}

// ---------------------------------------------------------------------------
// Kernel 1: rotation layers + bf16 pack + per-group row-sums (verified R8).
// Also zeroes g_sem (runs stream-ordered before k_gemm).
// ---------------------------------------------------------------------------
__global__ __launch_bounds__(1024) void k_rotate(
    const float* __restrict__ x,      // [16][4096] f32 (fp16 promoted)
    const float* __restrict__ theta,  // [8][2048]  f32
    const int*   __restrict__ pairs,  // [8][4096]  int32
    const float* __restrict__ cscale) // [4096]     f32
{
    __shared__ float row[IN_F];
    const int b   = blockIdx.x;
    const int tid = threadIdx.x;

    if (b == 0 && tid < 112) g_sem[tid] = 0;

    int2  ij0[KROT], ij1[KROT];
    float c0[KROT], s0[KROT], c1[KROT], s1[KROT];
#pragma unroll
    for (int k = 0; k < KROT; ++k) {
        const int2*  pk = (const int2*)(pairs + k * IN_F);
        const float* tk = theta + k * (IN_F / 2);
        ij0[k] = pk[tid];
        ij1[k] = pk[tid + 1024];
        __sincosf(tk[tid],        &s0[k], &c0[k]);
        __sincosf(tk[tid + 1024], &s1[k], &c1[k]);
    }

    for (int i = tid; i < IN_F; i += 1024) row[i] = x[b * IN_F + i];
    __syncthreads();

#pragma unroll
    for (int k = 0; k < KROT; ++k) {
        float a0 = row[ij0[k].x], b0 = row[ij0[k].y];
        float a1 = row[ij1[k].x], b1 = row[ij1[k].y];
        row[ij0[k].x] = c0[k] * a0 - s0[k] * b0;
        row[ij0[k].y] = s0[k] * a0 + c0[k] * b0;
        row[ij1[k].x] = c1[k] * a1 - s1[k] * b1;
        row[ij1[k].y] = s1[k] * a1 + c1[k] * b1;
        __syncthreads();
    }

    float p0, p1;
    {
        int i = tid;
        uint32_t lo = f2bf(row[2 * i]     * cscale[2 * i]);
        uint32_t hi = f2bf(row[2 * i + 1] * cscale[2 * i + 1]);
        g_xa[b * (IN_F / 2) + i] = lo | (hi << 16);
        p0 = bf2f(lo) + bf2f(hi);
        i = tid + 1024;
        lo = f2bf(row[2 * i]     * cscale[2 * i]);
        hi = f2bf(row[2 * i + 1] * cscale[2 * i + 1]);
        g_xa[b * (IN_F / 2) + i] = lo | (hi << 16);
        p1 = bf2f(lo) + bf2f(hi);
    }
#pragma unroll
    for (int m = 1; m < 64; m <<= 1) {
        p0 += __shfl_xor(p0, m, 64);
        p1 += __shfl_xor(p1, m, 64);
    }
    if ((tid & 63) == 0) {
        const int w = tid >> 6;
        g_rs[w * BATCH + b]        = p0;
        g_rs[(16 + w) * BATCH + b] = p1;
    }
}

// ---------------------------------------------------------------------------
// Kernel 2: MFMA dequant-GEMM (R10 structure: coalesced fetch, barrier-free
// wave-private K-split) + two new pieces:
//  (a) explicit 1-stage prefetch: next stage's 8 qweight words + A-frag are
//      issued before the current stage's dequant/MFMA. Meaningful now that
//      the main loop has NO barriers (R7's neutrality was barrier drain).
//  (b) last-block-reduces epilogue: the 4 K-chunk blocks of an n-slice sync
//      via device-scope semaphore; the last one sums g_part and writes d_out
//      -> k_reduce launch eliminated.
// ---------------------------------------------------------------------------
__global__ __launch_bounds__(256, 2) void k_gemm(
    const int*   __restrict__ qweight, // [4096][1792] int32
    const int*   __restrict__ qzeros,  // [32][1792]   int32
    const float* __restrict__ scales,  // [32][14336]  f32
    float*       __restrict__ out)     // [16][14336]  f32 = d_out
{
    __shared__ uint4 ldsb[4 * 512];    // 4 wave-private 8KB regions (32 KB)
    __shared__ int   s_last;

    const int tid  = threadIdx.x;
    const int bn   = blockIdx.x % 112;
    const int bk   = blockIdx.x / 112;    // K-chunk 0..3
    const int n0   = bn * 128;
    const int jp0  = bn * 16;             // 16 packed words per block row
    const int w    = tid >> 6;            // wave 0..3
    const int lane = tid & 63;
    const int jp   = lane & 15;           // staging word 0..15
    const int rr   = lane >> 4;           // staging k-octet 0..3
    const int mrow = lane & 15;           // MFMA m-row / n-col lane
    const int quad = lane >> 4;

    uint4* ldsw = ldsb + w * 512;

    // ---- prologue: hoist per-(group, n-tile) scales / zero-terms / rowsums
    float sv[2][8], tv[2][8];
    f32x4 rsv[2];
    {
        const int sh = 4 * (mrow & 7);
#pragma unroll
        for (int gi = 0; gi < 2; ++gi) {
            const int gg = bk * 8 + w * 2 + gi;
            rsv[gi] = *(const f32x4*)(g_rs + gg * BATCH + quad * 4);
#pragma unroll
            for (int t = 0; t < 8; ++t) {
                const int col = n0 + t * 16 + mrow;
                const float s = scales[(size_t)gg * OUT_F + col];
                const float z = 128.0f +
                    (float)(((uint32_t)qzeros[gg * NJP + (col >> 3)] >> sh) & 15u);
                sv[gi][t] = s;
                tv[gi][t] = s * z;
            }
        }
    }

    f32x4 m[8], ga[8];
#pragma unroll
    for (int t = 0; t < 8; ++t) {
        m[t]  = (f32x4){0.f, 0.f, 0.f, 0.f};
        ga[t] = (f32x4){0.f, 0.f, 0.f, 0.f};
    }

    // flat stage index it = gi*4 + sc; k-base of stage = group*128 + sc*32
    // wave w's k-range: groups bk*8 + w*2 + {0,1}
    const int kbase0 = (bk * 8 + w * 2) * GROUP;   // stage it: kbase0 + it*32

    uint32_t wc[8];
    uint4    ac;
    {
        const int kb = kbase0 + rr * 8;
#pragma unroll
        for (int i = 0; i < 8; ++i)
            wc[i] = (uint32_t)qweight[(size_t)(kb + i) * NJP + jp0 + jp];
        ac = *(const uint4*)(g_xa + mrow * (IN_F / 2) + (kbase0 >> 1) + quad * 4);
    }

#pragma unroll
    for (int it = 0; it < 8; ++it) {
        // ---- prefetch stage it+1 (in flight through dequant+MFMA below) ---
        uint32_t wn[8];
        uint4    an;
        if (it < 7) {
            const int kb1 = kbase0 + (it + 1) * 32 + rr * 8;
#pragma unroll
            for (int i = 0; i < 8; ++i)
                wn[i] = (uint32_t)qweight[(size_t)(kb1 + i) * NJP + jp0 + jp];
            an = *(const uint4*)(g_xa + mrow * (IN_F / 2)
                                 + ((kbase0 + (it + 1) * 32) >> 1) + quad * 4);
        }

        // ---- dequant: bf16(128+v) bit-OR; bank-spread col permutation -----
#pragma unroll
        for (int cc = 0; cc < 8; ++cc) {
            const int c  = cc ^ (jp & 7);
            const int sh = 4 * c;
            uint4 cell;
            uint32_t pk[4];
#pragma unroll
            for (int h = 0; h < 4; ++h) {
                uint32_t lo = (wc[2 * h]     >> sh) & 15u;
                uint32_t hi = (wc[2 * h + 1] >> sh) & 15u;
                pk[h] = 0x43004300u | lo | (hi << 16);
            }
            cell.x = pk[0]; cell.y = pk[1]; cell.z = pk[2]; cell.w = pk[3];
            ldsw[rr * 128 + jp * 8 + c] = cell;   // [k-octet][col]
        }

        // ---- wave-synchronous MFMA: 8 n-tiles, 1 k-tile -------------------
        union { uint4 q; short8 s; } af;
        af.q = ac;
#pragma unroll
        for (int t = 0; t < 8; ++t) {
            union { uint4 q; short8 s; } bf;
            bf.q = ldsw[quad * 128 + t * 16 + mrow];
            ga[t] = __builtin_amdgcn_mfma_f32_16x16x32_bf16(af.s, bf.s, ga[t], 0, 0, 0);
        }

        // ---- group boundary: fold scale + zero-point correction -----------
        if ((it & 3) == 3) {
            const int gi = it >> 2;
#pragma unroll
            for (int t = 0; t < 8; ++t) {
#pragma unroll
                for (int r = 0; r < 4; ++r)
                    m[t][r] = fmaf(sv[gi][t], ga[t][r],
                                   fmaf(-tv[gi][t], rsv[gi][r], m[t][r]));
                ga[t] = (f32x4){0.f, 0.f, 0.f, 0.f};
            }
        }

        if (it < 7) {
#pragma unroll
            for (int i = 0; i < 8; ++i) wc[i] = wn[i];
            ac = an;
        }
    }

    // ---- epilogue A: cross-wave reduction in LDS, store partial slice -----
    float* fw = (float*)ldsb + w * 2048;   // [row 16][col 128]
#pragma unroll
    for (int t = 0; t < 8; ++t)
#pragma unroll
        for (int r = 0; r < 4; ++r)
            fw[(quad * 4 + r) * 128 + t * 16 + mrow] = m[t][r];
    __syncthreads();

    const float* fb   = (const float*)ldsb;
    const int    colg = (tid & 31) * 4;    // 0..124
    const int    row  = tid >> 5;          // 0..7 (rows row and row+8)
    f32x4 sA = {0.f, 0.f, 0.f, 0.f}, sB = {0.f, 0.f, 0.f, 0.f};
#pragma unroll
    for (int ww = 0; ww < 4; ++ww) {
        sA += *(const f32x4*)(fb + ww * 2048 + row * 128 + colg);
        sB += *(const f32x4*)(fb + ww * 2048 + (row + 8) * 128 + colg);
    }
    float* pp = g_part + (size_t)bk * BATCH * OUT_F + n0 + colg;
    *(f32x4*)(pp + (size_t)row * OUT_F)       = sA;
    *(f32x4*)(pp + (size_t)(row + 8) * OUT_F) = sB;

    // ---- epilogue B: last block of this n-slice reduces K-chunks ----------
    __threadfence();      // release our partial stores (device scope)
    __syncthreads();      // all threads' stores+fences done before arrival
    if (tid == 0) {
        int old = __hip_atomic_fetch_add(&g_sem[bn], 1, __ATOMIC_ACQ_REL,
                                         __HIP_MEMORY_SCOPE_AGENT);
        s_last = (old == 3);
    }
    __syncthreads();
    if (s_last) {
        __threadfence();  // acquire side
        const int r2 = tid >> 4;           // 0..15
        const int c2 = (tid & 15) * 8;     // 0..120
        const size_t base = (size_t)r2 * OUT_F + n0 + c2;
        f32x4 a0 = {0.f, 0.f, 0.f, 0.f}, a1 = {0.f, 0.f, 0.f, 0.f};
#pragma unroll
        for (int kc = 0; kc < 4; ++kc) {
            const float* q = g_part + (size_t)kc * BATCH * OUT_F + base;
            a0 += *(const f32x4*)(q);
            a1 += *(const f32x4*)(q + 4);
        }
        *(f32x4*)(out + base)     = a0;
        *(f32x4*)(out + base + 4) = a1;
    }
}

extern "C" void kernel_launch(void* const* d_in, const int* in_sizes, int n_in,
                              void* d_out, int out_size, void* d_ws, size_t ws_size,
                              hipStream_t stream) {
    const float* x       = (const float*)d_in[0];
    const float* theta   = (const float*)d_in[1];
    const int*   pairs   = (const int*)d_in[2];
    const float* cscale  = (const float*)d_in[3];
    const int*   qweight = (const int*)d_in[4];
    const int*   qzeros  = (const int*)d_in[5];
    const float* scales  = (const float*)d_in[6];
    float*       out     = (float*)d_out;
    (void)d_ws; (void)ws_size;

    k_rotate<<<16, 1024, 0, stream>>>(x, theta, pairs, cscale);
    k_gemm<<<448, 256, 0, stream>>>(qweight, qzeros, scales, out);
}

// Round 12
// 103.430 us; speedup vs baseline: 1.5680x; 1.5680x over previous
//
#include <hip/hip_runtime.h>
#include <cstdint>

#define IN_F   4096
#define OUT_F  14336
#define GROUP  128
#define KROT   8
#define BATCH  16
#define NJP    1792           // packed words per weight row
#define NG     32             // quant groups

typedef __attribute__((ext_vector_type(8))) short short8;  // 8 bf16
typedef __attribute__((ext_vector_type(4))) float f32x4;

// Module-scope scratch (no d_ws dependence).
__device__ uint32_t g_xa[BATCH * IN_F / 2];    // rotated activations, bf16 pairs
__device__ float    g_rs[NG * BATCH];          // per-(group,row) sums of bf16 acts
__device__ float    g_part[4 * BATCH * OUT_F]; // 4 K-chunk fp32 partials

static __device__ __forceinline__ unsigned short f2bf(float f) {
    union { float f; uint32_t i; } v; v.f = f;
    uint32_t u = v.i;
    uint32_t r = u + 0x7FFFu + ((u >> 16) & 1u);  // RNE
    return (unsigned short)(r >> 16);
}
static __device__ __forceinline__ float bf2f(uint32_t u16) {
    union { uint32_t i; float f; } v; v.i = u16 << 16; return v.f;
}

// ---------------------------------------------------------------------------
// Kernel 1: rotation layers + bf16 pack + per-group row-sums (verified R8).
// ---------------------------------------------------------------------------
__global__ __launch_bounds__(1024) void k_rotate(
    const float* __restrict__ x,      // [16][4096] f32 (fp16 promoted)
    const float* __restrict__ theta,  // [8][2048]  f32
    const int*   __restrict__ pairs,  // [8][4096]  int32
    const float* __restrict__ cscale) // [4096]     f32
{
    __shared__ float row[IN_F];
    const int b   = blockIdx.x;
    const int tid = threadIdx.x;

    int2  ij0[KROT], ij1[KROT];
    float c0[KROT], s0[KROT], c1[KROT], s1[KROT];
#pragma unroll
    for (int k = 0; k < KROT; ++k) {
        const int2*  pk = (const int2*)(pairs + k * IN_F);
        const float* tk = theta + k * (IN_F / 2);
        ij0[k] = pk[tid];
        ij1[k] = pk[tid + 1024];
        __sincosf(tk[tid],        &s0[k], &c0[k]);
        __sincosf(tk[tid + 1024], &s1[k], &c1[k]);
    }

    for (int i = tid; i < IN_F; i += 1024) row[i] = x[b * IN_F + i];
    __syncthreads();

#pragma unroll
    for (int k = 0; k < KROT; ++k) {
        float a0 = row[ij0[k].x], b0 = row[ij0[k].y];
        float a1 = row[ij1[k].x], b1 = row[ij1[k].y];
        row[ij0[k].x] = c0[k] * a0 - s0[k] * b0;
        row[ij0[k].y] = s0[k] * a0 + c0[k] * b0;
        row[ij1[k].x] = c1[k] * a1 - s1[k] * b1;
        row[ij1[k].y] = s1[k] * a1 + c1[k] * b1;
        __syncthreads();
    }

    float p0, p1;
    {
        int i = tid;
        uint32_t lo = f2bf(row[2 * i]     * cscale[2 * i]);
        uint32_t hi = f2bf(row[2 * i + 1] * cscale[2 * i + 1]);
        g_xa[b * (IN_F / 2) + i] = lo | (hi << 16);
        p0 = bf2f(lo) + bf2f(hi);
        i = tid + 1024;
        lo = f2bf(row[2 * i]     * cscale[2 * i]);
        hi = f2bf(row[2 * i + 1] * cscale[2 * i + 1]);
        g_xa[b * (IN_F / 2) + i] = lo | (hi << 16);
        p1 = bf2f(lo) + bf2f(hi);
    }
#pragma unroll
    for (int m = 1; m < 64; m <<= 1) {
        p0 += __shfl_xor(p0, m, 64);
        p1 += __shfl_xor(p1, m, 64);
    }
    if ((tid & 63) == 0) {
        const int w = tid >> 6;
        g_rs[w * BATCH + b]        = p0;
        g_rs[(16 + w) * BATCH + b] = p1;
    }
}

// ---------------------------------------------------------------------------
// Kernel 2: MFMA dequant-GEMM. R10 structure (coalesced fetch, barrier-free
// wave-private K-split, plain-store epilogue) + R11's explicit 1-stage
// prefetch main loop. R11's semaphore/threadfence epilogue is REMOVED:
// device-scope fences measured catastrophic on CDNA4 (448 blocks x L2
// wb/inv = 75us of idle stall). k_reduce is a separate cheap launch.
// ---------------------------------------------------------------------------
__global__ __launch_bounds__(256, 2) void k_gemm(
    const int*   __restrict__ qweight, // [4096][1792] int32
    const int*   __restrict__ qzeros,  // [32][1792]   int32
    const float* __restrict__ scales)  // [32][14336]  f32
{
    __shared__ uint4 ldsb[4 * 512];    // 4 wave-private 8KB regions (32 KB)

    const int tid  = threadIdx.x;
    const int bn   = blockIdx.x % 112;
    const int bk   = blockIdx.x / 112;    // K-chunk 0..3
    const int n0   = bn * 128;
    const int jp0  = bn * 16;             // 16 packed words per block row
    const int w    = tid >> 6;            // wave 0..3
    const int lane = tid & 63;
    const int jp   = lane & 15;           // staging word 0..15
    const int rr   = lane >> 4;           // staging k-octet 0..3
    const int mrow = lane & 15;           // MFMA m-row / n-col lane
    const int quad = lane >> 4;

    uint4* ldsw = ldsb + w * 512;

    // ---- prologue: hoist per-(group, n-tile) scales / zero-terms / rowsums
    float sv[2][8], tv[2][8];
    f32x4 rsv[2];
    {
        const int sh = 4 * (mrow & 7);
#pragma unroll
        for (int gi = 0; gi < 2; ++gi) {
            const int gg = bk * 8 + w * 2 + gi;
            rsv[gi] = *(const f32x4*)(g_rs + gg * BATCH + quad * 4);
#pragma unroll
            for (int t = 0; t < 8; ++t) {
                const int col = n0 + t * 16 + mrow;
                const float s = scales[(size_t)gg * OUT_F + col];
                const float z = 128.0f +
                    (float)(((uint32_t)qzeros[gg * NJP + (col >> 3)] >> sh) & 15u);
                sv[gi][t] = s;
                tv[gi][t] = s * z;
            }
        }
    }

    f32x4 m[8], ga[8];
#pragma unroll
    for (int t = 0; t < 8; ++t) {
        m[t]  = (f32x4){0.f, 0.f, 0.f, 0.f};
        ga[t] = (f32x4){0.f, 0.f, 0.f, 0.f};
    }

    // flat stage it = 0..7 over this wave's 2 groups x 4 sub-chunks of 32k
    const int kbase0 = (bk * 8 + w * 2) * GROUP;

    uint32_t wc[8];
    uint4    ac;
    {
        const int kb = kbase0 + rr * 8;
#pragma unroll
        for (int i = 0; i < 8; ++i)
            wc[i] = (uint32_t)qweight[(size_t)(kb + i) * NJP + jp0 + jp];
        ac = *(const uint4*)(g_xa + mrow * (IN_F / 2) + (kbase0 >> 1) + quad * 4);
    }

#pragma unroll
    for (int it = 0; it < 8; ++it) {
        // ---- prefetch stage it+1 (in flight through dequant+MFMA below) ---
        uint32_t wn[8];
        uint4    an;
        if (it < 7) {
            const int kb1 = kbase0 + (it + 1) * 32 + rr * 8;
#pragma unroll
            for (int i = 0; i < 8; ++i)
                wn[i] = (uint32_t)qweight[(size_t)(kb1 + i) * NJP + jp0 + jp];
            an = *(const uint4*)(g_xa + mrow * (IN_F / 2)
                                 + ((kbase0 + (it + 1) * 32) >> 1) + quad * 4);
        }

        // ---- dequant: bf16(128+v) bit-OR; bank-spread col permutation -----
#pragma unroll
        for (int cc = 0; cc < 8; ++cc) {
            const int c  = cc ^ (jp & 7);
            const int sh = 4 * c;
            uint4 cell;
            uint32_t pk[4];
#pragma unroll
            for (int h = 0; h < 4; ++h) {
                uint32_t lo = (wc[2 * h]     >> sh) & 15u;
                uint32_t hi = (wc[2 * h + 1] >> sh) & 15u;
                pk[h] = 0x43004300u | lo | (hi << 16);
            }
            cell.x = pk[0]; cell.y = pk[1]; cell.z = pk[2]; cell.w = pk[3];
            ldsw[rr * 128 + jp * 8 + c] = cell;   // [k-octet][col]
        }

        // ---- wave-synchronous MFMA: 8 n-tiles, 1 k-tile -------------------
        union { uint4 q; short8 s; } af;
        af.q = ac;
#pragma unroll
        for (int t = 0; t < 8; ++t) {
            union { uint4 q; short8 s; } bf;
            bf.q = ldsw[quad * 128 + t * 16 + mrow];
            ga[t] = __builtin_amdgcn_mfma_f32_16x16x32_bf16(af.s, bf.s, ga[t], 0, 0, 0);
        }

        // ---- group boundary: fold scale + zero-point correction -----------
        if ((it & 3) == 3) {
            const int gi = it >> 2;
#pragma unroll
            for (int t = 0; t < 8; ++t) {
#pragma unroll
                for (int r = 0; r < 4; ++r)
                    m[t][r] = fmaf(sv[gi][t], ga[t][r],
                                   fmaf(-tv[gi][t], rsv[gi][r], m[t][r]));
                ga[t] = (f32x4){0.f, 0.f, 0.f, 0.f};
            }
        }

        if (it < 7) {
#pragma unroll
            for (int i = 0; i < 8; ++i) wc[i] = wn[i];
            ac = an;
        }
    }

    // ---- epilogue: cross-wave reduction in LDS, plain coalesced store -----
    float* fw = (float*)ldsb + w * 2048;   // [row 16][col 128]
#pragma unroll
    for (int t = 0; t < 8; ++t)
#pragma unroll
        for (int r = 0; r < 4; ++r)
            fw[(quad * 4 + r) * 128 + t * 16 + mrow] = m[t][r];
    __syncthreads();

    const float* fb   = (const float*)ldsb;
    const int    colg = (tid & 31) * 4;    // 0..124
    const int    row  = tid >> 5;          // 0..7 (rows row and row+8)
    f32x4 sA = {0.f, 0.f, 0.f, 0.f}, sB = {0.f, 0.f, 0.f, 0.f};
#pragma unroll
    for (int ww = 0; ww < 4; ++ww) {
        sA += *(const f32x4*)(fb + ww * 2048 + row * 128 + colg);
        sB += *(const f32x4*)(fb + ww * 2048 + (row + 8) * 128 + colg);
    }
    float* pp = g_part + (size_t)bk * BATCH * OUT_F + n0 + colg;
    *(f32x4*)(pp + (size_t)row * OUT_F)       = sA;
    *(f32x4*)(pp + (size_t)(row + 8) * OUT_F) = sB;
}

// ---------------------------------------------------------------------------
// Kernel 3: sum the 4 K-chunk partials -> d_out. float4 per thread.
// ---------------------------------------------------------------------------
__global__ __launch_bounds__(128) void k_reduce(float* __restrict__ out)
{
    const int t = blockIdx.x * 128 + threadIdx.x;   // 0..57343
    const size_t j = (size_t)t * 4;
    float4 a = *(const float4*)(g_part + j);
    float4 b = *(const float4*)(g_part + (size_t)BATCH * OUT_F + j);
    float4 c = *(const float4*)(g_part + (size_t)2 * BATCH * OUT_F + j);
    float4 d = *(const float4*)(g_part + (size_t)3 * BATCH * OUT_F + j);
    float4 s;
    s.x = (a.x + b.x) + (c.x + d.x);
    s.y = (a.y + b.y) + (c.y + d.y);
    s.z = (a.z + b.z) + (c.z + d.z);
    s.w = (a.w + b.w) + (c.w + d.w);
    *(float4*)(out + j) = s;
}

extern "C" void kernel_launch(void* const* d_in, const int* in_sizes, int n_in,
                              void* d_out, int out_size, void* d_ws, size_t ws_size,
                              hipStream_t stream) {
    const float* x       = (const float*)d_in[0];
    const float* theta   = (const float*)d_in[1];
    const int*   pairs   = (const int*)d_in[2];
    const float* cscale  = (const float*)d_in[3];
    const int*   qweight = (const int*)d_in[4];
    const int*   qzeros  = (const int*)d_in[5];
    const float* scales  = (const float*)d_in[6];
    float*       out     = (float*)d_out;
    (void)d_ws; (void)ws_size;

    k_rotate<<<16, 1024, 0, stream>>>(x, theta, pairs, cscale);
    k_gemm<<<448, 256, 0, stream>>>(qweight, qzeros, scales);
    k_reduce<<<(BATCH * OUT_F) / (128 * 4), 128, 0, stream>>>(out);
}